// Round 4
// baseline (273.318 us; speedup 1.0000x reference)
//
#include <hip/hip_runtime.h>
#include <math.h>

#define HH 1080
#define WW 1920
#define RAD 5
#define TX 32
#define TY 32
#define RPT 4
#define BDY 8
#define LR (TY + 2*RAD)   // 42
#define LC (TX + 2*RAD)   // 42

typedef float f32x2 __attribute__((ext_vector_type(2)));

__device__ __forceinline__ float fast_rcp(float x) {
#if __has_builtin(__builtin_amdgcn_rcpf)
    return __builtin_amdgcn_rcpf(x);
#else
    return 1.0f / x;
#endif
}
__device__ __forceinline__ float fast_rsq(float x) {
#if __has_builtin(__builtin_amdgcn_rsqf)
    return __builtin_amdgcn_rsqf(x);
#else
    return rsqrtf(x);
#endif
}
__device__ __forceinline__ float fast_log2(float x) {
#if __has_builtin(__builtin_amdgcn_logf)
    return __builtin_amdgcn_logf(x);
#else
    return __log2f(x);
#endif
}
__device__ __forceinline__ float fast_exp2(float x) {
#if __has_builtin(__builtin_amdgcn_exp2f)
    return __builtin_amdgcn_exp2f(x);
#else
    return exp2f(x);
#endif
}

// Weight: w = exp(-d2/8) * clip(dot,0,1)^128 * exp(-|tz-z| / max(dz*sqrt(d2), 1e-4))
// Fused:  w = exp2( T.cxy[d2] + 128*log2(max(dot,0)) - |tz-z| * min(rdz*T.rsd[d2], 1e4*log2e) )
//   T is a 51-entry LDS table over the wave-uniform integer d2 = dy^2+dx^2:
//     T[d2] = { -d2 * log2e/8,  log2e * rsqrt(d2) }    (broadcast ds_read_b64, no VALU)
//   rdz = rcp(dz) hoisted per center; 1/max(a,eps) == min(1/a, 1/eps).
// Center tap: rsd[0]=inf -> tm clamps to BIG=1e4*log2e (== the reference eps clamp), zd==0 ->
//   fma(-0,BIG,eb)=eb; dot==1 -> w=1. Exact. dz==0: rdz=inf -> tm=BIG == reference max(0,1e-4) path.
// Zero-padded halo: normals 0 -> dot 0 -> log2(0)=-inf -> w=0, reproducing reference mask t_m.
// (Numerics of this fusion validated R2/R3: absmax 3.9e-3 vs threshold 2e-2.)

__global__ __launch_bounds__(TX*BDY, 3)
void denoise_kernel(const float* __restrict__ in, float* __restrict__ out) {
    __shared__ float4 sA[LR][LC];   // c0,c1,c2,n0   28224 B
    __shared__ float2 sN[LR][LC];   // n1,n2         14112 B
    __shared__ float  sZ[LR][LC];   // z              7056 B
    __shared__ float2 sT[51];       // {cxy, rsd}      408 B -> 49800 B total -> 3 blocks/CU

    const int tx = threadIdx.x;
    const int ty = threadIdx.y;
    const int tid = ty * TX + tx;
    const int x0 = blockIdx.x * TX;
    const int y0 = blockIdx.y * TY;

    // ---- fill the d2 table (wave-uniform lookups later) ----
    if (tid < 51) {
        float d2f = (float)tid;
        sT[tid] = make_float2(-0.18033688011112042f * d2f,          // -d2 * log2e/8
                              1.4426950408889634f * fast_rsq(d2f)); // log2e/sqrt(d2), inf at 0
    }

    // ---- stage tile + halo, normalizing normals on the fly ----
    #pragma unroll
    for (int i = 0; i < (LR * LC + TX * BDY - 1) / (TX * BDY); ++i) {
        int idx = tid + i * (TX * BDY);
        if (idx < LR * LC) {
            int r = idx / LC, c = idx % LC;
            int gx = x0 + c - RAD;
            int gy = y0 + r - RAD;
            float4 a = make_float4(0.f, 0.f, 0.f, 0.f);
            float4 b = make_float4(0.f, 0.f, 0.f, 0.f);
            if ((unsigned)gx < (unsigned)WW && (unsigned)gy < (unsigned)HH) {
                const float4* p = reinterpret_cast<const float4*>(in + ((size_t)gy * WW + gx) * 8);
                a = p[0];
                b = p[1];
            }
            float nn = a.w * a.w + b.x * b.x + b.y * b.y;
            float s = fast_rsq(fmaxf(nn, 1e-20f));
            sA[r][c] = make_float4(a.x, a.y, a.z, a.w * s);
            sN[r][c] = make_float2(b.x * s, b.y * s);
            sZ[r][c] = b.z;
        }
    }
    __syncthreads();

    // ---- per-thread centers: 4 vertically adjacent outputs ----
    float cn0[RPT], cn1[RPT], cn2[RPT], cz[RPT], rdz[RPT];
    #pragma unroll
    for (int o = 0; o < RPT; ++o) {
        int rr = ty * RPT + RAD + o, cc = tx + RAD;
        float4 A = sA[rr][cc];
        float2 N = sN[rr][cc];
        cn0[o] = A.w; cn1[o] = N.x; cn2[o] = N.y; cz[o] = sZ[rr][cc];
        int gy = y0 + ty * RPT + o;
        float dzv = 1.0f;
        if (gy < HH) dzv = in[(((size_t)gy * WW) + (x0 + tx)) * 8 + 7];
        rdz[o] = fast_rcp(dzv);
    }

    f32x2 accA[RPT];   // {c0, c1}
    f32x2 accB[RPT];   // {c2, w}
    #pragma unroll
    for (int o = 0; o < RPT; ++o) { accA[o] = (f32x2)0.f; accB[o] = (f32x2)0.f; }

    // ---- main tap loop: RUNTIME r loop (14 iters) -- do NOT unroll (R2 spill lesson);
    //      each tap read from LDS once, reused by up to 4 outputs ----
    for (int r = 0; r < 2 * RAD + RPT; ++r) {
        int  dy2i[RPT];
        bool val[RPT];
        #pragma unroll
        for (int o = 0; o < RPT; ++o) {
            int dy = r - RAD - o;
            val[o] = (dy >= -RAD) && (dy <= RAD);
            dy2i[o] = dy * dy;
        }
        #pragma unroll
        for (int dx = 0; dx < 2 * RAD + 1; ++dx) {
            float4 A  = sA[ty * RPT + r][tx + dx];
            float2 N  = sN[ty * RPT + r][tx + dx];
            float  tz = sZ[ty * RPT + r][tx + dx];
            const int DX2 = (dx - RAD) * (dx - RAD);
            f32x2 Axy = {A.x, A.y};
            f32x2 Czw = {A.z, 1.0f};
            #pragma unroll
            for (int o = 0; o < RPT; ++o) {
                if (val[o]) {
                    float2 T  = sT[dy2i[o] + DX2];                 // broadcast ds_read_b64
                    float dot = fmaf(A.w, cn0[o], fmaf(N.x, cn1[o], N.y * cn2[o]));
                    float lg  = fast_log2(fmaxf(dot, 0.0f));       // -inf at 0 -> w=0
                    float eb  = fmaf(lg, 128.0f, T.x);
                    float tm  = fminf(rdz[o] * T.y, 14426.950408889634f);  // 1e4*log2e
                    float zd  = tz - cz[o];
                    float e2  = fmaf(-fabsf(zd), tm, eb);
                    float w   = fast_exp2(e2);
                    f32x2 wv  = {w, w};
                    accA[o] = __builtin_elementwise_fma(Axy, wv, accA[o]);  // v_pk_fma_f32
                    accB[o] = __builtin_elementwise_fma(Czw, wv, accB[o]);
                }
            }
        }
    }

    // ---- epilogue ----
    const int xo = x0 + tx;
    #pragma unroll
    for (int o = 0; o < RPT; ++o) {
        int y = y0 + ty * RPT + o;
        if (y < HH) {
            float inv = fast_rcp(accB[o].y);
            size_t base = ((size_t)y * WW + xo) * 3;
            out[base + 0] = accA[o].x * inv;
            out[base + 1] = accA[o].y * inv;
            out[base + 2] = accB[o].x * inv;
        }
    }
}

extern "C" void kernel_launch(void* const* d_in, const int* in_sizes, int n_in,
                              void* d_out, int out_size, void* d_ws, size_t ws_size,
                              hipStream_t stream) {
    const float* in = (const float*)d_in[0];
    float* out = (float*)d_out;
    dim3 grid((WW + TX - 1) / TX, (HH + TY - 1) / TY);   // 60 x 34
    dim3 block(TX, BDY);                                  // 256 threads
    hipLaunchKernelGGL(denoise_kernel, grid, block, 0, stream, in, out);
}

// Round 5
// 123.559 us; speedup vs baseline: 2.2120x; 2.2120x over previous
//
#include <hip/hip_runtime.h>
#include <math.h>

#define HH 1080
#define WW 1920
#define RAD 5
#define TX 32
#define TY 32
#define RPT 4
#define BDY 8
#define LR (TY + 2*RAD)   // 42
#define LC (TX + 2*RAD)   // 42

__device__ __forceinline__ float fast_rcp(float x) {
#if __has_builtin(__builtin_amdgcn_rcpf)
    return __builtin_amdgcn_rcpf(x);
#else
    return 1.0f / x;
#endif
}
__device__ __forceinline__ float fast_rsq(float x) {
#if __has_builtin(__builtin_amdgcn_rsqf)
    return __builtin_amdgcn_rsqf(x);
#else
    return rsqrtf(x);
#endif
}
__device__ __forceinline__ float fast_log2(float x) {
#if __has_builtin(__builtin_amdgcn_logf)
    return __builtin_amdgcn_logf(x);
#else
    return __log2f(x);
#endif
}
__device__ __forceinline__ float fast_exp2(float x) {
#if __has_builtin(__builtin_amdgcn_exp2f)
    return __builtin_amdgcn_exp2f(x);
#else
    return exp2f(x);
#endif
}

// Weight: w = exp(-d2/8) * clip(dot,0,1)^128 * exp(-|tz-z| / max(dz*sqrt(d2), 1e-4))
// Fused:  w = exp2( -c*d2 + 128*log2(max(dot,0)) - |tz-z| * min(rdz*rsqrt(d2), 1e4*log2e) )
//   c = log2e/8, rdz = log2e * rcp(dz) hoisted per center; 1/max(a,eps) == min(1/a,1/eps).
// For a fixed tap-row (r) and center (o), d2 takes only 6 values (dx^2 in {0,1,4,9,16,25}),
// so {cx, tm} are hoisted into per-(o,k) REGISTER tables at the top of each r iteration and
// indexed by the compile-time k = |dx-RAD| in the body (R4 lesson: registers, not LDS).
// Center tap: rsqrt(0)=inf -> tm clamps to BIG; zd==0 -> fma(-0,BIG,eb)=eb; dot==1 -> w=1. Exact.
// Zero-padded halo: normals 0 -> dot 0 -> log2(0) = -inf -> w = 0 == reference mask t_m.
// (Numerics validated R2/R3/R4: absmax 3.9e-3 vs threshold 2e-2.)

__global__ __launch_bounds__(TX*BDY, 3)
void denoise_kernel(const float* __restrict__ in, float* __restrict__ out) {
    __shared__ float4 sA[LR][LC];   // c0,c1,c2,n0   28224 B
    __shared__ float2 sN[LR][LC];   // n1,n2         14112 B
    __shared__ float  sZ[LR][LC];   // z              7056 B -> 49392 B -> 3 blocks/CU

    const int tx = threadIdx.x;
    const int ty = threadIdx.y;
    const int tid = ty * TX + tx;
    const int x0 = blockIdx.x * TX;
    const int y0 = blockIdx.y * TY;

    // ---- stage tile + halo, normalizing normals on the fly ----
    #pragma unroll
    for (int i = 0; i < (LR * LC + TX * BDY - 1) / (TX * BDY); ++i) {
        int idx = tid + i * (TX * BDY);
        if (idx < LR * LC) {
            int r = idx / LC, c = idx % LC;
            int gx = x0 + c - RAD;
            int gy = y0 + r - RAD;
            float4 a = make_float4(0.f, 0.f, 0.f, 0.f);
            float4 b = make_float4(0.f, 0.f, 0.f, 0.f);
            if ((unsigned)gx < (unsigned)WW && (unsigned)gy < (unsigned)HH) {
                const float4* p = reinterpret_cast<const float4*>(in + ((size_t)gy * WW + gx) * 8);
                a = p[0];
                b = p[1];
            }
            float nn = a.w * a.w + b.x * b.x + b.y * b.y;
            float s = fast_rsq(fmaxf(nn, 1e-20f));
            sA[r][c] = make_float4(a.x, a.y, a.z, a.w * s);
            sN[r][c] = make_float2(b.x * s, b.y * s);
            sZ[r][c] = b.z;
        }
    }
    __syncthreads();

    // ---- per-thread centers: 4 vertically adjacent outputs ----
    float cn0[RPT], cn1[RPT], cn2[RPT], cz[RPT], rdz[RPT];
    #pragma unroll
    for (int o = 0; o < RPT; ++o) {
        int rr = ty * RPT + RAD + o, cc = tx + RAD;
        float4 A = sA[rr][cc];
        float2 N = sN[rr][cc];
        cn0[o] = A.w; cn1[o] = N.x; cn2[o] = N.y; cz[o] = sZ[rr][cc];
        int gy = y0 + ty * RPT + o;
        float dzv = 1.0f;
        if (gy < HH) dzv = in[(((size_t)gy * WW) + (x0 + tx)) * 8 + 7];
        rdz[o] = 1.4426950408889634f * fast_rcp(dzv);   // log2e folded in
    }

    float accx[RPT] = {0.f, 0.f, 0.f, 0.f};
    float accy[RPT] = {0.f, 0.f, 0.f, 0.f};
    float accz[RPT] = {0.f, 0.f, 0.f, 0.f};
    float accw[RPT] = {0.f, 0.f, 0.f, 0.f};

    // ROW_BODY(CHECK): one tap-row. Hoists per-(o,k) {cx,tm} register tables, then the
    // 11x4 unrolled bodies use compile-time k = |dx-RAD|. CHECK=false -> branch-free.
    #define ROW_BODY(CHECK)                                                          \
    {                                                                                \
        float tmv[RPT][RAD + 1], cxv[RPT][RAD + 1];                                  \
        bool  val[RPT];                                                              \
        _Pragma("unroll")                                                            \
        for (int o = 0; o < RPT; ++o) {                                              \
            int dy = r - RAD - o;                                                    \
            val[o] = (dy >= -RAD) && (dy <= RAD);                                    \
            float dy2 = (float)(dy * dy);                                            \
            _Pragma("unroll")                                                        \
            for (int k = 0; k <= RAD; ++k) {                                         \
                const float K2 = (float)(k * k);                                     \
                float d2 = dy2 + K2;                                                 \
                cxv[o][k] = d2 * -0.18033688011112042f;                              \
                tmv[o][k] = fminf(rdz[o] * fast_rsq(d2), 14426.950408889634f);       \
            }                                                                        \
        }                                                                            \
        _Pragma("unroll")                                                            \
        for (int dx = 0; dx < 2 * RAD + 1; ++dx) {                                   \
            float4 A  = sA[ty * RPT + r][tx + dx];                                   \
            float2 N  = sN[ty * RPT + r][tx + dx];                                   \
            float  tz = sZ[ty * RPT + r][tx + dx];                                   \
            const int k = (dx < RAD) ? (RAD - dx) : (dx - RAD);                      \
            _Pragma("unroll")                                                        \
            for (int o = 0; o < RPT; ++o) {                                          \
                if (!CHECK || val[o]) {                                              \
                    float dot = fmaf(A.w, cn0[o], fmaf(N.x, cn1[o], N.y * cn2[o]));  \
                    float lg  = fast_log2(fmaxf(dot, 0.0f));                         \
                    float eb  = fmaf(lg, 128.0f, cxv[o][k]);                         \
                    float zd  = tz - cz[o];                                          \
                    float e2  = fmaf(-fabsf(zd), tmv[o][k], eb);                     \
                    float w   = fast_exp2(e2);                                       \
                    accx[o] = fmaf(A.x, w, accx[o]);                                 \
                    accy[o] = fmaf(A.y, w, accy[o]);                                 \
                    accz[o] = fmaf(A.z, w, accz[o]);                                 \
                    accw[o] += w;                                                    \
                }                                                                    \
            }                                                                        \
        }                                                                            \
    }

    // ---- boundary rows (some o invalid) ----
    #pragma unroll 1
    for (int r = 0; r < RPT - 1; ++r) ROW_BODY(true)
    // ---- steady rows r in [3,10]: all 4 outputs valid, branch-free ----
    #pragma unroll 1
    for (int r = RPT - 1; r <= 2 * RAD; ++r) ROW_BODY(false)
    // ---- boundary rows ----
    #pragma unroll 1
    for (int r = 2 * RAD + 1; r < 2 * RAD + RPT; ++r) ROW_BODY(true)

    #undef ROW_BODY

    // ---- epilogue ----
    const int xo = x0 + tx;
    #pragma unroll
    for (int o = 0; o < RPT; ++o) {
        int y = y0 + ty * RPT + o;
        if (y < HH) {
            float inv = fast_rcp(accw[o]);
            size_t base = ((size_t)y * WW + xo) * 3;
            out[base + 0] = accx[o] * inv;
            out[base + 1] = accy[o] * inv;
            out[base + 2] = accz[o] * inv;
        }
    }
}

extern "C" void kernel_launch(void* const* d_in, const int* in_sizes, int n_in,
                              void* d_out, int out_size, void* d_ws, size_t ws_size,
                              hipStream_t stream) {
    const float* in = (const float*)d_in[0];
    float* out = (float*)d_out;
    dim3 grid((WW + TX - 1) / TX, (HH + TY - 1) / TY);   // 60 x 34
    dim3 block(TX, BDY);                                  // 256 threads
    hipLaunchKernelGGL(denoise_kernel, grid, block, 0, stream, in, out);
}